// Round 1
// 503.327 us; speedup vs baseline: 1.0122x; 1.0122x over previous
//
#include <hip/hip_runtime.h>

#define B_GRAPHS 1024
#define NN 360
#define HH 8
#define DD 256
#define D4 64          // DD / 4 float4 lanes
#define ROWS_PER_WAVE 90
#define CHUNK 6        // 90 = 15 * 6

// ---------------------------------------------------------------------------
// Kernel 0: softmax over nodes per head, computed ONCE (1 block) into d_ws.
// attn[n][h] = softmax_n(w[:, h])[n]
// ---------------------------------------------------------------------------
__global__ __launch_bounds__(256) void roigp_softmax_kernel(
        const float* __restrict__ w, float* __restrict__ attn) {
    const int lane = threadIdx.x & 63;
    const int wave = threadIdx.x >> 6;

    #pragma unroll
    for (int h = wave; h < HH; h += 4) {
        float m = -1e30f;
        for (int n = lane; n < NN; n += 64) m = fmaxf(m, w[n * HH + h]);
        #pragma unroll
        for (int off = 32; off > 0; off >>= 1) m = fmaxf(m, __shfl_xor(m, off));

        float s = 0.f;
        for (int n = lane; n < NN; n += 64) s += __expf(w[n * HH + h] - m);
        #pragma unroll
        for (int off = 32; off > 0; off >>= 1) s += __shfl_xor(s, off);

        const float inv = 1.f / s;
        for (int n = lane; n < NN; n += 64)
            attn[n * HH + h] = __expf(w[n * HH + h] - m) * inv;
    }
}

// ---------------------------------------------------------------------------
// Kernel 1: out[b][h][d] = sum_n x[b][n][d] * attn[n][h]
// One block per graph, 256 threads (4 waves). Lane = float4 column slice.
// Wave owns a contiguous 90-row slab. Chunked loads (6 rows in flight) keep
// the live VGPR set ~100, safely under the 128 cap from (256,4).
// LDS: attn buffer (11.52 KB) overlaid by the cross-wave reduction buffer.
// ---------------------------------------------------------------------------
__global__ __launch_bounds__(256, 4) void roigp_fused_kernel(
        const float4* __restrict__ x,
        const float4* __restrict__ attn4,   // [NN*HH/4] float4, from d_ws
        float4* __restrict__ out) {
    __shared__ __align__(16) char smem[4 * HH * D4 * 16];   // 32 KB
    float* s_attn = (float*)smem;                            // first 11.52 KB
    float4 (*s_red)[HH][D4] = (float4 (*)[HH][D4])smem;

    const int b    = blockIdx.x;
    const int lane = threadIdx.x & 63;
    const int wave = threadIdx.x >> 6;

    // ---- Load precomputed attn into LDS (720 float4, coalesced, 3 rounds).
    float4* s_attn4 = (float4*)s_attn;
    #pragma unroll
    for (int i = threadIdx.x; i < NN * HH / 4; i += 256)
        s_attn4[i] = attn4[i];
    __syncthreads();

    // ---- Main streaming loop: contiguous 90-row slab per wave.
    const int n0 = wave * ROWS_PER_WAVE;
    const float4* __restrict__ xp = x + ((size_t)b * NN + n0) * D4 + lane;

    float4 acc[HH];
    #pragma unroll
    for (int h = 0; h < HH; ++h) acc[h] = make_float4(0.f, 0.f, 0.f, 0.f);

    #pragma unroll 1
    for (int c = 0; c < ROWS_PER_WAVE / CHUNK; ++c) {
        // 6 coalesced row loads in flight (24 VGPRs)
        float4 xq[CHUNK];
        #pragma unroll
        for (int j = 0; j < CHUNK; ++j)
            xq[j] = xp[(size_t)(c * CHUNK + j) * D4];

        #pragma unroll
        for (int j = 0; j < CHUNK; ++j) {
            const float4 xv = xq[j];
            const float* ap = s_attn + (n0 + c * CHUNK + j) * HH;
            const float4 a0 = *(const float4*)ap;        // LDS broadcast
            const float4 a1 = *(const float4*)(ap + 4);
#define FMA4(A, S) \
            A.x = fmaf(xv.x, S, A.x); A.y = fmaf(xv.y, S, A.y); \
            A.z = fmaf(xv.z, S, A.z); A.w = fmaf(xv.w, S, A.w);
            FMA4(acc[0], a0.x) FMA4(acc[1], a0.y)
            FMA4(acc[2], a0.z) FMA4(acc[3], a0.w)
            FMA4(acc[4], a1.x) FMA4(acc[5], a1.y)
            FMA4(acc[6], a1.z) FMA4(acc[7], a1.w)
#undef FMA4
        }
    }

    // ---- Cross-wave reduction. attn is dead; reuse the LDS.
    __syncthreads();   // all waves done READING s_attn before overwrite
    #pragma unroll
    for (int h = 0; h < HH; ++h) s_red[wave][h][lane] = acc[h];
    __syncthreads();

    // 8 heads x 64 float4 = 512 output slots; 256 threads -> 2 each
    #pragma unroll
    for (int s = threadIdx.x; s < HH * D4; s += 256) {
        const int h = s >> 6, l = s & 63;
        const float4 r0 = s_red[0][h][l];
        const float4 r1 = s_red[1][h][l];
        const float4 r2 = s_red[2][h][l];
        const float4 r3 = s_red[3][h][l];
        float4 o;
        o.x = r0.x + r1.x + r2.x + r3.x;
        o.y = r0.y + r1.y + r2.y + r3.y;
        o.z = r0.z + r1.z + r2.z + r3.z;
        o.w = r0.w + r1.w + r2.w + r3.w;
        out[(size_t)b * (HH * D4) + s] = o;
    }
}

extern "C" void kernel_launch(void* const* d_in, const int* in_sizes, int n_in,
                              void* d_out, int out_size, void* d_ws, size_t ws_size,
                              hipStream_t stream) {
    const float* x = (const float*)d_in[0];   // [B*360, 256] fp32
    // d_in[1] = batch (int64) — dense/sorted by construction; unused.
    const float* w = (const float*)d_in[2];   // [360, 8] fp32
    float* attn = (float*)d_ws;               // [360*8] fp32 scratch

    roigp_softmax_kernel<<<1, 256, 0, stream>>>(w, attn);
    roigp_fused_kernel<<<B_GRAPHS, 256, 0, stream>>>(
        (const float4*)x, (const float4*)attn, (float4*)d_out);
}